// Round 4
// baseline (1626.250 us; speedup 1.0000x reference)
//
#include <hip/hip_runtime.h>

typedef unsigned int u32;
typedef unsigned short u16;
typedef u16 u16x8 __attribute__((ext_vector_type(8)));
typedef u16 u16x4 __attribute__((ext_vector_type(4)));
typedef __bf16 bf16x8 __attribute__((ext_vector_type(8)));
typedef __bf16 bf16x4v __attribute__((ext_vector_type(4)));
typedef float f32x4 __attribute__((ext_vector_type(4)));
typedef float f32x2 __attribute__((ext_vector_type(2)));

#define B_SZ 32
#define S_SZ 128
#define T_SZ 127
#define DK 128
#define SKILL 256
#define RL 136   /* hS row pitch (u16): 128 + 8 pad, keeps rows 16B-aligned */

__device__ __forceinline__ u16x4 cvt4(f32x4 v) {
    return __builtin_bit_cast(u16x4, __builtin_convertvector(v, bf16x4v));
}
__device__ __forceinline__ u16x8 cvt8(f32x4 a, f32x4 b) {
    u16x4 x = cvt4(a), y = cvt4(b);
    u16x8 r;
    r[0]=x[0]; r[1]=x[1]; r[2]=x[2]; r[3]=x[3];
    r[4]=y[0]; r[5]=y[1]; r[6]=y[2]; r[7]=y[3];
    return r;
}
__device__ __forceinline__ u16 bfu(float x) {
    return __builtin_bit_cast(u16, (__bf16)x);
}
__device__ __forceinline__ float sigm(float x) {
    float e = __builtin_amdgcn_exp2f(-1.44269504f * x);
    return __builtin_amdgcn_rcpf(1.f + e);
}
__device__ __forceinline__ float tanh_f(float x) {
    float e = __builtin_amdgcn_exp2f(-2.88539008f * x);
    return 2.f * __builtin_amdgcn_rcpf(1.f + e) - 1.f;
}
__device__ __forceinline__ f32x4 mfma16(u16x8 a, u16x8 bb, f32x4 c) {
    return __builtin_amdgcn_mfma_f32_16x16x32_bf16(
        __builtin_bit_cast(bf16x8, a), __builtin_bit_cast(bf16x8, bb), c, 0, 0, 0);
}

// ---------------------------------------------------------------------------
// Kernel A: le[b,t,:] = W1 @ [ex | at | ans] + b1 ; one (b,t) per block
// ---------------------------------------------------------------------------
__global__ __launch_bounds__(128) void k_le(
    const int* __restrict__ eid, const int* __restrict__ atime,
    const int* __restrict__ ansv, const float* __restrict__ ex_t,
    const float* __restrict__ at_t, const float* __restrict__ W1,
    const float* __restrict__ b1, float* __restrict__ le_ws)
{
    int t = blockIdx.x, b = blockIdx.y, d = threadIdx.x;
    __shared__ float exS[128], atS[128];
    int e = eid[b * S_SZ + t];
    int a = atime[b * S_SZ + t];
    float av = (float)ansv[b * S_SZ + t];
    exS[d] = ex_t[e * DK + d];
    atS[d] = at_t[a * DK + d];
    __syncthreads();
    const float* wr = W1 + d * 384;
    float acc = b1[d];
    float wsum = 0.f;
    #pragma unroll 8
    for (int k4 = 0; k4 < 32; ++k4) {
        f32x4 w = *(const f32x4*)(wr + 4 * k4);
        acc += w[0] * exS[4 * k4] + w[1] * exS[4 * k4 + 1]
             + w[2] * exS[4 * k4 + 2] + w[3] * exS[4 * k4 + 3];
    }
    #pragma unroll 8
    for (int k4 = 32; k4 < 64; ++k4) {
        f32x4 w = *(const f32x4*)(wr + 4 * k4);
        acc += w[0] * atS[4 * k4 - 128] + w[1] * atS[4 * k4 - 127]
             + w[2] * atS[4 * k4 - 126] + w[3] * atS[4 * k4 - 125];
    }
    #pragma unroll 8
    for (int k4 = 64; k4 < 96; ++k4) {
        f32x4 w = *(const f32x4*)(wr + 4 * k4);
        wsum += w[0] + w[1] + w[2] + w[3];
    }
    acc += av * wsum;
    le_ws[(b * T_SZ + t) * DK + d] = acc;
}

// ---------------------------------------------------------------------------
// Kernel B: input-only gate pre-activations ; one (b,t) per block
// ---------------------------------------------------------------------------
__global__ __launch_bounds__(128) void k_pre(
    const int* __restrict__ itime, const float* __restrict__ it_t,
    const float* __restrict__ Wl, const float* __restrict__ blv,
    const float* __restrict__ Wg, const float* __restrict__ bgv,
    const float* __restrict__ Wf, const float* __restrict__ bfv,
    const float* __restrict__ le_ws,
    float* __restrict__ PRE_l, float* __restrict__ PRE_g, float* __restrict__ PRE_f)
{
    int t = blockIdx.x, b = blockIdx.y, o = threadIdx.x;
    __shared__ float lp[128], lc[128], itS[128];
    int iv = itime[b * S_SZ + t + 1];
    itS[o] = it_t[iv * DK + o];
    lc[o] = le_ws[(b * T_SZ + t) * DK + o];
    lp[o] = (t == 0) ? 0.f : le_ws[(b * T_SZ + t - 1) * DK + o];
    __syncthreads();
    const float* wl = Wl + o * 512;
    const float* wg = Wg + o * 512;
    float al = blv[o], ag = bgv[o];
    #pragma unroll 8
    for (int k4 = 0; k4 < 32; ++k4) {
        f32x4 w  = *(const f32x4*)(wl + 4 * k4);
        f32x4 w2 = *(const f32x4*)(wg + 4 * k4);
        #pragma unroll
        for (int j = 0; j < 4; ++j) {
            float x = lp[4 * k4 + j];
            al += w[j] * x; ag += w2[j] * x;
        }
    }
    #pragma unroll 8
    for (int k4 = 32; k4 < 64; ++k4) {
        f32x4 w  = *(const f32x4*)(wl + 4 * k4);
        f32x4 w2 = *(const f32x4*)(wg + 4 * k4);
        #pragma unroll
        for (int j = 0; j < 4; ++j) {
            float x = itS[4 * k4 - 128 + j];
            al += w[j] * x; ag += w2[j] * x;
        }
    }
    #pragma unroll 8
    for (int k4 = 64; k4 < 96; ++k4) {
        f32x4 w  = *(const f32x4*)(wl + 4 * k4);
        f32x4 w2 = *(const f32x4*)(wg + 4 * k4);
        #pragma unroll
        for (int j = 0; j < 4; ++j) {
            float x = lc[4 * k4 - 256 + j];
            al += w[j] * x; ag += w2[j] * x;
        }
    }
    float af = bfv[o];
    const float* wf = Wf + o * 384 + 256;
    #pragma unroll 8
    for (int k4 = 0; k4 < 32; ++k4) {
        f32x4 w = *(const f32x4*)(wf + 4 * k4);
        af += w[0] * itS[4 * k4] + w[1] * itS[4 * k4 + 1]
            + w[2] * itS[4 * k4 + 2] + w[3] * itS[4 * k4 + 3];
    }
    size_t idx = (size_t)(b * T_SZ + t) * DK + o;
    PRE_l[idx] = al;
    PRE_g[idx] = ag;
    PRE_f[idx] = af;
}

// ---------------------------------------------------------------------------
// Kernel C: sequential scan, 1024 threads (16 waves, 4 waves/SIMD).
// Wave (ih2 = w&3: d-quarter, 2 m-tiles) x (js = w>>2: skill-quarter, 4 n-tiles)
// Per step: Zf-h1 MFMA -> z MFMA (h~ hi/lo) -> LG ->[B]-> c MFMA ->[C]->
//           update-h1 -> Zf-h2 ->[D]-> update-h2 -> butterfly/partW ->[E]->
//           reduce h~ ->[TOP]
// ---------------------------------------------------------------------------
__global__ __launch_bounds__(1024, 1) void k_main(
    const int* __restrict__ eid, const float* __restrict__ qmat,
    const float* __restrict__ Wl, const float* __restrict__ Wg,
    const float* __restrict__ Wf, const float* __restrict__ h0,
    const float* __restrict__ PRE_l, const float* __restrict__ PRE_g,
    const float* __restrict__ PRE_f, float* __restrict__ ht_ws)
{
    extern __shared__ char smem[];
    u16*   hS    = (u16*)smem;                    // [256][136] bf16 = 69632
    float* kvS   = (float*)(smem + 69632);        // [2][256]          2048
    float* partW = (float*)(smem + 71680);        // [4][132]          2112
    u16*   htbf  = (u16*)(smem + 73792);          // hi[128] lo[128]    512
    u16*   LGb   = (u16*)(smem + 74304);          // hi[128] lo[128]    512
    float* LGf   = (float*)(smem + 74816);        // [128]              512
    float* cS    = (float*)(smem + 75328);        // [128]              512

    const int b    = blockIdx.x;
    const int tid  = threadIdx.x;
    const int w    = tid >> 6;
    const int lane = tid & 63;
    const int quad = lane >> 4;
    const int l4   = lane & 15;
    const int ih2  = w & 3;    // d-quarter
    const int js   = w >> 2;   // skill-quarter
    const int tc   = w & 7;    // c-tile

    // ---- persistent A-frags ----
    u16x8 afr[2][4];   // Wf1 rows (Zf): m = 32*ih2+16*mt+l4
    #pragma unroll
    for (int mt = 0; mt < 2; ++mt)
        #pragma unroll
        for (int kt = 0; kt < 4; ++kt) {
            const float* p = Wf + (32 * ih2 + 16 * mt + l4) * 384 + 32 * kt + quad * 8;
            afr[mt][kt] = cvt8(*(const f32x4*)p, *(const f32x4*)(p + 4));
        }
    u16x8 azf[4];      // z-tile w: row rho = 16w+l4 (interleaved zl/zg)
    {
        int rho = 16 * w + l4;
        const float* base = (rho & 1) ? Wg : Wl;
        const float* rp = base + (rho >> 1) * 512 + 384;
        #pragma unroll
        for (int kt = 0; kt < 4; ++kt) {
            const float* p = rp + 32 * kt + quad * 8;
            azf[kt] = cvt8(*(const f32x4*)p, *(const f32x4*)(p + 4));
        }
    }
    u16x8 acf[4];      // c-tile tc: Wf2 row m = 16*tc+l4
    #pragma unroll
    for (int kt = 0; kt < 4; ++kt) {
        const float* p = Wf + (16 * tc + l4) * 384 + 128 + 32 * kt + quad * 8;
        acf[kt] = cvt8(*(const f32x4*)p, *(const f32x4*)(p + 4));
    }

    // ---- h0 -> fp32 regs (C-layout) + bf16 LDS mirror ----
    f32x4 hreg[2][4];
    #pragma unroll
    for (int mt = 0; mt < 2; ++mt) {
        int d0 = 32 * ih2 + 16 * mt + quad * 4;
        #pragma unroll
        for (int nt = 0; nt < 4; ++nt) {
            int s = 64 * js + 16 * nt + l4;
            f32x4 hv = *(const f32x4*)(h0 + s * DK + d0);
            hreg[mt][nt] = hv;
            *(u16x4*)(hS + s * RL + d0) = cvt4(hv);
        }
    }
    if (tid < 256) kvS[tid] = qmat[eid[b * S_SZ] * SKILL + tid];
    __syncthreads();

    // ---- h~_0 = kv0^T @ h0 ----
    {
        float hp[8];
        #pragma unroll
        for (int v = 0; v < 8; ++v) hp[v] = 0.f;
        #pragma unroll
        for (int nt = 0; nt < 4; ++nt) {
            float kv = kvS[64 * js + 16 * nt + l4];
            #pragma unroll
            for (int mt = 0; mt < 2; ++mt)
                #pragma unroll
                for (int r = 0; r < 4; ++r)
                    hp[mt * 4 + r] += kv * hreg[mt][nt][r];
        }
        #pragma unroll
        for (int mk = 1; mk <= 8; mk <<= 1)
            #pragma unroll
            for (int v = 0; v < 8; ++v)
                hp[v] += __shfl_xor(hp[v], mk, 64);
        if (l4 < 8) {
            float v = hp[0];
            #pragma unroll
            for (int i = 1; i < 8; ++i) v = (l4 == i) ? hp[i] : v;
            partW[js * 132 + 32 * ih2 + 16 * (l4 >> 2) + quad * 4 + (l4 & 3)] = v;
        }
        __syncthreads();
        if (tid < 128) {
            float v = partW[tid] + partW[132 + tid] + partW[264 + tid] + partW[396 + tid];
            float hf = (float)(__bf16)v;
            htbf[tid] = bfu(v);
            htbf[128 + tid] = bfu(v - hf);
        }
        __syncthreads();
    }

    for (int t = 0; t < T_SZ; ++t) {
        const int p = t & 1;
        const size_t tb = (size_t)(b * T_SZ + t) * DK;
        // ---- prefetch kv_{t+1} ----
        int en = eid[b * S_SZ + t + 1];
        if (tid < 256) kvS[(1 - p) * 256 + tid] = qmat[en * SKILL + tid];

        // ---- Zf half-1 (nt 0..1): reads h_t rows [64js, 64js+32) ----
        f32x4 accF[2][2];
        #pragma unroll
        for (int mt = 0; mt < 2; ++mt)
            #pragma unroll
            for (int n2 = 0; n2 < 2; ++n2)
                accF[mt][n2] = (f32x4){0.f, 0.f, 0.f, 0.f};
        #pragma unroll
        for (int n2 = 0; n2 < 2; ++n2) {
            const u16* bp = hS + (64 * js + 16 * n2 + l4) * RL + quad * 8;
            #pragma unroll
            for (int kt = 0; kt < 4; ++kt) {
                u16x8 bfr = *(const u16x8*)(bp + kt * 32);
                accF[0][n2] = mfma16(afr[0][kt], bfr, accF[0][n2]);
                accF[1][n2] = mfma16(afr[1][kt], bfr, accF[1][n2]);
            }
        }

        // ---- z MFMA: A = W4 rows (azf), B = h~ broadcast (hi+lo) ----
        f32x4 accZ = (f32x4){0.f, 0.f, 0.f, 0.f};
        #pragma unroll
        for (int kt = 0; kt < 4; ++kt) {
            u16x8 bh = *(const u16x8*)(htbf + 32 * kt + quad * 8);
            u16x8 bl = *(const u16x8*)(htbf + 128 + 32 * kt + quad * 8);
            accZ = mfma16(azf[kt], bh, accZ);
            accZ = mfma16(azf[kt], bl, accZ);
        }
        // lane holds z[16w + quad*4 + r] (identical across l4)
        if (l4 == 0) {
            int d0 = 8 * w + 2 * quad;    // rho pairs (2d0,2d0+1),(2d0+2,2d0+3)
            f32x2 pl2 = *(const f32x2*)(PRE_l + tb + d0);
            f32x2 pg2 = *(const f32x2*)(PRE_g + tb + d0);
            float LG0 = sigm(accZ[1] + pg2[0]) * (tanh_f(accZ[0] + pl2[0]) + 1.f) * 0.5f;
            float LG1 = sigm(accZ[3] + pg2[1]) * (tanh_f(accZ[2] + pl2[1]) + 1.f) * 0.5f;
            float h0f = (float)(__bf16)LG0;
            float h1f = (float)(__bf16)LG1;
            *(u32*)(LGb + d0) = (u32)bfu(LG0) | ((u32)bfu(LG1) << 16);
            *(u32*)(LGb + 128 + d0) = (u32)bfu(LG0 - h0f) | ((u32)bfu(LG1 - h1f) << 16);
            *(f32x2*)(LGf + d0) = (f32x2){LG0, LG1};
        }
        __syncthreads();   // B: LG ready; all h1 hS-reads done; kvS next ready

        // ---- c MFMA: A = Wf2 rows (acf), B = LG broadcast (hi+lo) ----
        {
            f32x4 accC = (f32x4){0.f, 0.f, 0.f, 0.f};
            #pragma unroll
            for (int kt = 0; kt < 4; ++kt) {
                u16x8 bh = *(const u16x8*)(LGb + 32 * kt + quad * 8);
                u16x8 bl = *(const u16x8*)(LGb + 128 + 32 * kt + quad * 8);
                accC = mfma16(acf[kt], bh, accC);
                accC = mfma16(acf[kt], bl, accC);
            }
            if (w < 8 && l4 == 0) {
                f32x4 pf = *(const f32x4*)(PRE_f + tb + 16 * tc + quad * 4);
                *(f32x4*)(cS + 16 * tc + quad * 4) = accC + pf;
            }
        }
        __syncthreads();   // C: c ready

        // ---- update half-1 (nt 0..1) ----
        float hp[8];
        #pragma unroll
        for (int v = 0; v < 8; ++v) hp[v] = 0.f;
        #pragma unroll
        for (int mt = 0; mt < 2; ++mt) {
            int d0 = 32 * ih2 + 16 * mt + quad * 4;
            f32x4 lg = *(const f32x4*)(LGf + d0);
            f32x4 cc = *(const f32x4*)(cS + d0);
            #pragma unroll
            for (int n2 = 0; n2 < 2; ++n2) {
                int s = 64 * js + 16 * n2 + l4;
                float ktv = kvS[p * 256 + s];
                float knv = kvS[(1 - p) * 256 + s];
                f32x4 hv;
                #pragma unroll
                for (int r = 0; r < 4; ++r) {
                    float f = sigm(accF[mt][n2][r] + cc[r]);
                    float hn = ktv * lg[r] + f * hreg[mt][n2][r];
                    hreg[mt][n2][r] = hn;
                    hp[mt * 4 + r] += knv * hn;
                    hv[r] = hn;
                }
                *(u16x4*)(hS + s * RL + d0) = cvt4(hv);
            }
        }
        // ---- Zf half-2 (nt 2..3): reads rows [64js+32, 64js+64) (not yet rewritten) ----
        #pragma unroll
        for (int mt = 0; mt < 2; ++mt)
            #pragma unroll
            for (int n2 = 0; n2 < 2; ++n2)
                accF[mt][n2] = (f32x4){0.f, 0.f, 0.f, 0.f};
        #pragma unroll
        for (int n2 = 0; n2 < 2; ++n2) {
            const u16* bp = hS + (64 * js + 16 * (2 + n2) + l4) * RL + quad * 8;
            #pragma unroll
            for (int kt = 0; kt < 4; ++kt) {
                u16x8 bfr = *(const u16x8*)(bp + kt * 32);
                accF[0][n2] = mfma16(afr[0][kt], bfr, accF[0][n2]);
                accF[1][n2] = mfma16(afr[1][kt], bfr, accF[1][n2]);
            }
        }
        __syncthreads();   // D: all h2 hS-reads done before h2 writes (race fix)

        // ---- update half-2 (nt 2..3) ----
        #pragma unroll
        for (int mt = 0; mt < 2; ++mt) {
            int d0 = 32 * ih2 + 16 * mt + quad * 4;
            f32x4 lg = *(const f32x4*)(LGf + d0);
            f32x4 cc = *(const f32x4*)(cS + d0);
            #pragma unroll
            for (int n2 = 0; n2 < 2; ++n2) {
                int nt = 2 + n2;
                int s = 64 * js + 16 * nt + l4;
                float ktv = kvS[p * 256 + s];
                float knv = kvS[(1 - p) * 256 + s];
                f32x4 hv;
                #pragma unroll
                for (int r = 0; r < 4; ++r) {
                    float f = sigm(accF[mt][n2][r] + cc[r]);
                    float hn = ktv * lg[r] + f * hreg[mt][nt][r];
                    hreg[mt][nt][r] = hn;
                    hp[mt * 4 + r] += knv * hn;
                    hv[r] = hn;
                }
                *(u16x4*)(hS + s * RL + d0) = cvt4(hv);
            }
        }
        // ---- butterfly over l4 + partW scatter ----
        #pragma unroll
        for (int mk = 1; mk <= 8; mk <<= 1)
            #pragma unroll
            for (int v = 0; v < 8; ++v)
                hp[v] += __shfl_xor(hp[v], mk, 64);
        if (l4 < 8) {
            float v = hp[0];
            #pragma unroll
            for (int i = 1; i < 8; ++i) v = (l4 == i) ? hp[i] : v;
            partW[js * 132 + 32 * ih2 + 16 * (l4 >> 2) + quad * 4 + (l4 & 3)] = v;
        }
        __syncthreads();   // E: partials ready
        if (tid < 128) {
            float v = partW[tid] + partW[132 + tid] + partW[264 + tid] + partW[396 + tid];
            float hf = (float)(__bf16)v;
            htbf[tid] = bfu(v);
            htbf[128 + tid] = bfu(v - hf);
            ht_ws[tb + tid] = v;
        }
        __syncthreads();   // TOP: h~ ready, partW free
    }
}

// ---------------------------------------------------------------------------
// Kernel D: pred[b,t] = sigm(Wp @ [ex[b,t+1] | h_tilde[b,t]] + bp)
// ---------------------------------------------------------------------------
__global__ __launch_bounds__(128) void k_pred(
    const int* __restrict__ eid, const float* __restrict__ ex_t,
    const float* __restrict__ Wp, const float* __restrict__ bpv,
    const float* __restrict__ ht_ws, float* __restrict__ out)
{
    int t = blockIdx.x, b = blockIdx.y, d = threadIdx.x;
    __shared__ float exS[128], htS[128];
    int e = eid[b * S_SZ + t + 1];
    exS[d] = ex_t[e * DK + d];
    htS[d] = ht_ws[(size_t)(b * T_SZ + t) * DK + d];
    __syncthreads();
    const float* wr = Wp + d * 256;
    float z = bpv[d];
    #pragma unroll 8
    for (int k4 = 0; k4 < 32; ++k4) {
        f32x4 w = *(const f32x4*)(wr + 4 * k4);
        z += w[0] * exS[4 * k4] + w[1] * exS[4 * k4 + 1]
           + w[2] * exS[4 * k4 + 2] + w[3] * exS[4 * k4 + 3];
    }
    #pragma unroll 8
    for (int k4 = 32; k4 < 64; ++k4) {
        f32x4 w = *(const f32x4*)(wr + 4 * k4);
        z += w[0] * htS[4 * k4 - 128] + w[1] * htS[4 * k4 - 127]
           + w[2] * htS[4 * k4 - 126] + w[3] * htS[4 * k4 - 125];
    }
    out[(size_t)(b * T_SZ + t) * DK + d] = sigm(z);
}

extern "C" void kernel_launch(void* const* d_in, const int* in_sizes, int n_in,
                              void* d_out, int out_size, void* d_ws, size_t ws_size,
                              hipStream_t stream) {
    const int* eid     = (const int*)d_in[0];
    const int* atime   = (const int*)d_in[1];
    const int* itime   = (const int*)d_in[2];
    const int* ansv    = (const int*)d_in[3];
    const float* qmat  = (const float*)d_in[4];
    const float* ex_t  = (const float*)d_in[5];
    const float* at_t  = (const float*)d_in[6];
    const float* it_t  = (const float*)d_in[7];
    const float* W1    = (const float*)d_in[8];
    const float* b1    = (const float*)d_in[9];
    const float* Wl    = (const float*)d_in[10];
    const float* blv   = (const float*)d_in[11];
    const float* Wg    = (const float*)d_in[12];
    const float* bgv   = (const float*)d_in[13];
    const float* Wf    = (const float*)d_in[14];
    const float* bfv   = (const float*)d_in[15];
    const float* Wp    = (const float*)d_in[16];
    const float* bpv   = (const float*)d_in[17];
    const float* h0    = (const float*)d_in[18];
    float* out = (float*)d_out;

    const size_t SZ = (size_t)B_SZ * T_SZ * DK;
    float* wsf   = (float*)d_ws;
    float* le_ws = wsf;
    float* PRE_l = wsf + SZ;
    float* PRE_g = wsf + 2 * SZ;
    float* PRE_f = wsf + 3 * SZ;
    float* ht_ws = wsf + 4 * SZ;

    hipFuncSetAttribute((const void*)k_main,
                        hipFuncAttributeMaxDynamicSharedMemorySize, 75840);

    dim3 g(T_SZ, B_SZ);
    k_le  <<<g, 128, 0, stream>>>(eid, atime, ansv, ex_t, at_t, W1, b1, le_ws);
    k_pre <<<g, 128, 0, stream>>>(itime, it_t, Wl, blv, Wg, bgv, Wf, bfv,
                                  le_ws, PRE_l, PRE_g, PRE_f);
    k_main<<<dim3(B_SZ), 1024, 75840, stream>>>(eid, qmat, Wl, Wg, Wf, h0,
                                                PRE_l, PRE_g, PRE_f, ht_ws);
    k_pred<<<g, 128, 0, stream>>>(eid, ex_t, Wp, bpv, ht_ws, out);
}

// Round 6
// 1444.020 us; speedup vs baseline: 1.1262x; 1.1262x over previous
//
#include <hip/hip_runtime.h>

typedef unsigned int u32;
typedef unsigned short u16;
typedef u16 u16x8 __attribute__((ext_vector_type(8)));
typedef u16 u16x4 __attribute__((ext_vector_type(4)));
typedef __bf16 bf16x8 __attribute__((ext_vector_type(8)));
typedef __bf16 bf16x4v __attribute__((ext_vector_type(4)));
typedef float f32x4 __attribute__((ext_vector_type(4)));
typedef float f32x2 __attribute__((ext_vector_type(2)));

#define B_SZ 32
#define S_SZ 128
#define T_SZ 127
#define DK 128
#define SKILL 256
#define RL 136   /* hS row pitch (u16): 128 + 8 pad */
#define PP 68    /* part row pitch (f32): 64 + 4 pad */

#define NLOG2E  (-1.44269504f)
#define N2LOG2E (-2.88539008f)

__device__ __forceinline__ u16x4 cvt4(f32x4 v) {
    return __builtin_bit_cast(u16x4, __builtin_convertvector(v, bf16x4v));
}
__device__ __forceinline__ u16x8 cvt8s(f32x4 a, f32x4 b, float s) {
    u16x4 x = cvt4(a * s), y = cvt4(b * s);
    u16x8 r;
    r[0]=x[0]; r[1]=x[1]; r[2]=x[2]; r[3]=x[3];
    r[4]=y[0]; r[5]=y[1]; r[6]=y[2]; r[7]=y[3];
    return r;
}
__device__ __forceinline__ u16 bfu(float x) {
    return __builtin_bit_cast(u16, (__bf16)x);
}
__device__ __forceinline__ f32x4 mfma16(u16x8 a, u16x8 bb, f32x4 c) {
    return __builtin_amdgcn_mfma_f32_16x16x32_bf16(
        __builtin_bit_cast(bf16x8, a), __builtin_bit_cast(bf16x8, bb), c, 0, 0, 0);
}
__device__ __forceinline__ float sigm(float x) {   // plain sigmoid (k_pred)
    float e = __builtin_amdgcn_exp2f(NLOG2E * x);
    return __builtin_amdgcn_rcpf(1.f + e);
}

// ---------------------------------------------------------------------------
// Kernel B (fused le+pre): one (b,t) per block.
//   le_t, le_{t-1} computed in-block from tables; outputs PRE-SCALED:
//   PRE_l = -2log2e*(bl + Wl1@le_{t-1} + Wl2@it + Wl3@le_t)
//   PRE_g = -log2e *(bg + Wg1@le_{t-1} + Wg2@it + Wg3@le_t)
//   PRE_f = -log2e *(bf + Wf3@it)
// ---------------------------------------------------------------------------
__global__ __launch_bounds__(128) void k_pre(
    const int* __restrict__ eid, const int* __restrict__ atime,
    const int* __restrict__ ansv, const int* __restrict__ itime,
    const float* __restrict__ ex_t, const float* __restrict__ at_t,
    const float* __restrict__ it_t,
    const float* __restrict__ W1, const float* __restrict__ b1,
    const float* __restrict__ Wl, const float* __restrict__ blv,
    const float* __restrict__ Wg, const float* __restrict__ bgv,
    const float* __restrict__ Wf, const float* __restrict__ bfv,
    float* __restrict__ PRE_l, float* __restrict__ PRE_g, float* __restrict__ PRE_f)
{
    int t = blockIdx.x, b = blockIdx.y, o = threadIdx.x;
    __shared__ float xS[256];
    __shared__ float lp[128], lc[128], itS[128];
    const float* wr1 = W1 + o * 384;

    // ---- le_t -> lc ----
    {
        int e = eid[b * S_SZ + t], a = atime[b * S_SZ + t];
        float av = (float)ansv[b * S_SZ + t];
        xS[o] = ex_t[e * DK + o];
        xS[128 + o] = at_t[a * DK + o];
        __syncthreads();
        float acc = b1[o], wsum = 0.f;
        #pragma unroll 8
        for (int k4 = 0; k4 < 64; ++k4) {
            f32x4 w = *(const f32x4*)(wr1 + 4 * k4);
            acc += w[0] * xS[4 * k4] + w[1] * xS[4 * k4 + 1]
                 + w[2] * xS[4 * k4 + 2] + w[3] * xS[4 * k4 + 3];
        }
        #pragma unroll 8
        for (int k4 = 64; k4 < 96; ++k4) {
            f32x4 w = *(const f32x4*)(wr1 + 4 * k4);
            wsum += w[0] + w[1] + w[2] + w[3];
        }
        lc[o] = acc + av * wsum;
        __syncthreads();
    }
    // ---- le_{t-1} -> lp ----
    if (t > 0) {
        int e = eid[b * S_SZ + t - 1], a = atime[b * S_SZ + t - 1];
        float av = (float)ansv[b * S_SZ + t - 1];
        xS[o] = ex_t[e * DK + o];
        xS[128 + o] = at_t[a * DK + o];
        __syncthreads();
        float acc = b1[o], wsum = 0.f;
        #pragma unroll 8
        for (int k4 = 0; k4 < 64; ++k4) {
            f32x4 w = *(const f32x4*)(wr1 + 4 * k4);
            acc += w[0] * xS[4 * k4] + w[1] * xS[4 * k4 + 1]
                 + w[2] * xS[4 * k4 + 2] + w[3] * xS[4 * k4 + 3];
        }
        #pragma unroll 8
        for (int k4 = 64; k4 < 96; ++k4) {
            f32x4 w = *(const f32x4*)(wr1 + 4 * k4);
            wsum += w[0] + w[1] + w[2] + w[3];
        }
        lp[o] = acc + av * wsum;
    } else {
        lp[o] = 0.f;
    }
    int iv = itime[b * S_SZ + t + 1];
    itS[o] = it_t[iv * DK + o];
    __syncthreads();

    const float* wl = Wl + o * 512;
    const float* wg = Wg + o * 512;
    float al = blv[o], ag = bgv[o];
    #pragma unroll 8
    for (int k4 = 0; k4 < 32; ++k4) {
        f32x4 w  = *(const f32x4*)(wl + 4 * k4);
        f32x4 w2 = *(const f32x4*)(wg + 4 * k4);
        #pragma unroll
        for (int j = 0; j < 4; ++j) {
            float x = lp[4 * k4 + j];
            al += w[j] * x; ag += w2[j] * x;
        }
    }
    #pragma unroll 8
    for (int k4 = 32; k4 < 64; ++k4) {
        f32x4 w  = *(const f32x4*)(wl + 4 * k4);
        f32x4 w2 = *(const f32x4*)(wg + 4 * k4);
        #pragma unroll
        for (int j = 0; j < 4; ++j) {
            float x = itS[4 * k4 - 128 + j];
            al += w[j] * x; ag += w2[j] * x;
        }
    }
    #pragma unroll 8
    for (int k4 = 64; k4 < 96; ++k4) {
        f32x4 w  = *(const f32x4*)(wl + 4 * k4);
        f32x4 w2 = *(const f32x4*)(wg + 4 * k4);
        #pragma unroll
        for (int j = 0; j < 4; ++j) {
            float x = lc[4 * k4 - 256 + j];
            al += w[j] * x; ag += w2[j] * x;
        }
    }
    float af = bfv[o];
    const float* wf = Wf + o * 384 + 256;
    #pragma unroll 8
    for (int k4 = 0; k4 < 32; ++k4) {
        f32x4 w = *(const f32x4*)(wf + 4 * k4);
        af += w[0] * itS[4 * k4] + w[1] * itS[4 * k4 + 1]
            + w[2] * itS[4 * k4 + 2] + w[3] * itS[4 * k4 + 3];
    }
    size_t idx = (size_t)(b * T_SZ + t) * DK + o;
    PRE_l[idx] = N2LOG2E * al;
    PRE_g[idx] = NLOG2E * ag;
    PRE_f[idx] = NLOG2E * af;
}

// ---------------------------------------------------------------------------
// Kernel C: sequential scan, 512 threads (8 waves). Wave (ih=w&1: d-half) x
// (jh=w>>1: skill-quarter). Pre-scaled weights; f = rcp(1+2^(accF+cc)),
// LG = rcp((1+2^zl')(1+2^zg')). Zf-h1 for step t+1 overlaps the h~ reduce.
// Barriers/step: B, C, D, E, TOP.
// ---------------------------------------------------------------------------
__global__ __launch_bounds__(512, 1) void k_main(
    const int* __restrict__ eid, const float* __restrict__ qmat,
    const float* __restrict__ Wl, const float* __restrict__ Wg,
    const float* __restrict__ Wf, const float* __restrict__ h0,
    const float* __restrict__ PRE_l, const float* __restrict__ PRE_g,
    const float* __restrict__ PRE_f, float* __restrict__ ht_ws)
{
    extern __shared__ char smem[];
    u16*   hS   = (u16*)smem;                    // 256*136*2 = 69632
    float* part = (float*)(smem + 69632);        // 128*68*4 = 34816 -> 104448
    u16*   htbf = (u16*)(smem + 104448);         // hi[128] lo[128] -> 104960
    u16*   LGb  = (u16*)(smem + 104960);         // hi[128] lo[128] -> 105472
    float* LGf  = (float*)(smem + 105472);       // 128 -> 105984
    float* cS   = (float*)(smem + 105984);       // 128 -> 106496

    const int b    = blockIdx.x;
    const int tid  = threadIdx.x;
    const int w    = tid >> 6;
    const int lane = tid & 63;
    const int quad = lane >> 4;
    const int l4   = lane & 15;
    const int ih   = w & 1;
    const int jh   = w >> 1;

    // ---- persistent A-frags (pre-scaled) ----
    u16x8 afr[4][4];   // Wf1 * -log2e : m = 64ih+16mt+l4
    #pragma unroll
    for (int mt = 0; mt < 4; ++mt)
        #pragma unroll
        for (int kt = 0; kt < 4; ++kt) {
            const float* p = Wf + (64 * ih + 16 * mt + l4) * 384 + 32 * kt + quad * 8;
            afr[mt][kt] = cvt8s(*(const f32x4*)p, *(const f32x4*)(p + 4), NLOG2E);
        }
    u16x8 azf[2][4];   // stacked [Wl4;Wg4] rows rho=32w+16mt+l4; zl rows *-2log2e, zg *-log2e
    #pragma unroll
    for (int mt = 0; mt < 2; ++mt) {
        int rho = 32 * w + 16 * mt + l4;
        float sc = (rho & 1) ? NLOG2E : N2LOG2E;
        const float* base = (rho & 1) ? Wg : Wl;
        const float* rp = base + (rho >> 1) * 512 + 384;
        #pragma unroll
        for (int kt = 0; kt < 4; ++kt) {
            const float* p = rp + 32 * kt + quad * 8;
            azf[mt][kt] = cvt8s(*(const f32x4*)p, *(const f32x4*)(p + 4), sc);
        }
    }
    u16x8 acf[4];      // Wf2 * -log2e : m = 16w+l4
    #pragma unroll
    for (int kt = 0; kt < 4; ++kt) {
        const float* p = Wf + (16 * w + l4) * 384 + 128 + 32 * kt + quad * 8;
        acf[kt] = cvt8s(*(const f32x4*)p, *(const f32x4*)(p + 4), NLOG2E);
    }

    // ---- h0 -> fp32 regs (C-layout) + bf16 LDS mirror ----
    f32x4 hreg[4][4];   // [mt][nt]
    #pragma unroll
    for (int mt = 0; mt < 4; ++mt) {
        int d0 = 64 * ih + 16 * mt + quad * 4;
        #pragma unroll
        for (int nt = 0; nt < 4; ++nt) {
            int s = 64 * jh + 16 * nt + l4;
            f32x4 hv = *(const f32x4*)(h0 + s * DK + d0);
            hreg[mt][nt] = hv;
            *(u16x4*)(hS + s * RL + d0) = cvt4(hv);
        }
    }
    float kvt[4];
    {
        int e0 = eid[b * S_SZ];
        #pragma unroll
        for (int nt = 0; nt < 4; ++nt)
            kvt[nt] = qmat[e0 * SKILL + 64 * jh + 16 * nt + l4];
    }
    // ---- h~0 partial scatter ----
    {
        float hp[16];
        #pragma unroll
        for (int v = 0; v < 16; ++v) hp[v] = 0.f;
        #pragma unroll
        for (int nt = 0; nt < 4; ++nt)
            #pragma unroll
            for (int mt = 0; mt < 4; ++mt)
                #pragma unroll
                for (int r = 0; r < 4; ++r)
                    hp[mt * 4 + r] += kvt[nt] * hreg[mt][nt][r];
        #pragma unroll
        for (int mt = 0; mt < 4; ++mt)
            #pragma unroll
            for (int r = 0; r < 4; ++r)
                part[(64 * ih + 16 * mt + quad * 4 + r) * PP + jh * 16 + l4] = hp[mt * 4 + r];
    }
    __syncthreads();
    // ---- h~0 reduce ----
    {
        int d = tid >> 2, kq = tid & 3;
        const float* pp = part + d * PP + kq * 16;
        float v = 0.f;
        #pragma unroll
        for (int i4 = 0; i4 < 4; ++i4) {
            f32x4 x = *(const f32x4*)(pp + 4 * i4);
            v += x[0] + x[1] + x[2] + x[3];
        }
        v += __shfl_xor(v, 1, 64);
        v += __shfl_xor(v, 2, 64);
        if (kq == 0) {
            float hf = (float)(__bf16)v;
            htbf[d] = bfu(v);
            htbf[128 + d] = bfu(v - hf);
        }
    }
    // ---- Zf-h1 for t=0 (reads hS, already sync'd above) ----
    f32x4 accF[4][2];
    #pragma unroll
    for (int mt = 0; mt < 4; ++mt)
        #pragma unroll
        for (int n2 = 0; n2 < 2; ++n2)
            accF[mt][n2] = (f32x4){0.f, 0.f, 0.f, 0.f};
    #pragma unroll
    for (int n2 = 0; n2 < 2; ++n2) {
        const u16* bp = hS + (64 * jh + 16 * n2 + l4) * RL + quad * 8;
        #pragma unroll
        for (int kt = 0; kt < 4; ++kt) {
            u16x8 bfr = *(const u16x8*)(bp + kt * 32);
            #pragma unroll
            for (int mt = 0; mt < 4; ++mt)
                accF[mt][n2] = mfma16(afr[mt][kt], bfr, accF[mt][n2]);
        }
    }
    __syncthreads();   // TOP (h~0 + accF ready)

    const float* pPl = PRE_l + (size_t)b * T_SZ * DK;
    const float* pPg = PRE_g + (size_t)b * T_SZ * DK;
    const float* pPf = PRE_f + (size_t)b * T_SZ * DK;
    float*       pHt = ht_ws + (size_t)b * T_SZ * DK;
    const int*   pE  = eid + b * S_SZ;

    for (int t = 0; t < T_SZ; ++t) {
        // ---- prefetch kv_{t+1} ----
        int en = pE[t + 1];
        float kvn[4];
        #pragma unroll
        for (int nt = 0; nt < 4; ++nt)
            kvn[nt] = qmat[en * SKILL + 64 * jh + 16 * nt + l4];

        // ---- z MFMA (2 tiles, hi/lo split accumulators) ----
        f32x4 aZh0 = {0.f,0.f,0.f,0.f}, aZl0 = {0.f,0.f,0.f,0.f};
        f32x4 aZh1 = {0.f,0.f,0.f,0.f}, aZl1 = {0.f,0.f,0.f,0.f};
        #pragma unroll
        for (int kt = 0; kt < 4; ++kt) {
            u16x8 bh = *(const u16x8*)(htbf + 32 * kt + quad * 8);
            u16x8 bl = *(const u16x8*)(htbf + 128 + 32 * kt + quad * 8);
            aZh0 = mfma16(azf[0][kt], bh, aZh0);
            aZl0 = mfma16(azf[0][kt], bl, aZl0);
            aZh1 = mfma16(azf[1][kt], bh, aZh1);
            aZl1 = mfma16(azf[1][kt], bl, aZl1);
        }
        if (l4 == 0) {
            #pragma unroll
            for (int mt = 0; mt < 2; ++mt) {
                f32x4 acc = mt ? (aZh1 + aZl1) : (aZh0 + aZl0);
                int d0 = 16 * w + 8 * mt + 2 * quad;
                f32x2 pl2 = *(const f32x2*)(pPl + d0);
                f32x2 pg2 = *(const f32x2*)(pPg + d0);
                float e0l = __builtin_amdgcn_exp2f(acc[0] + pl2[0]);
                float e0g = __builtin_amdgcn_exp2f(acc[1] + pg2[0]);
                float LG0 = __builtin_amdgcn_rcpf((1.f + e0l) * (1.f + e0g));
                float e1l = __builtin_amdgcn_exp2f(acc[2] + pl2[1]);
                float e1g = __builtin_amdgcn_exp2f(acc[3] + pg2[1]);
                float LG1 = __builtin_amdgcn_rcpf((1.f + e1l) * (1.f + e1g));
                float h0f = (float)(__bf16)LG0;
                float h1f = (float)(__bf16)LG1;
                *(u32*)(LGb + d0) = (u32)bfu(LG0) | ((u32)bfu(LG1) << 16);
                *(u32*)(LGb + 128 + d0) = (u32)bfu(LG0 - h0f) | ((u32)bfu(LG1 - h1f) << 16);
                *(f32x2*)(LGf + d0) = (f32x2){LG0, LG1};
            }
        }
        __syncthreads();   // B: LG ready

        // ---- c MFMA (tile w) ----
        {
            f32x4 aCh = {0.f,0.f,0.f,0.f}, aCl = {0.f,0.f,0.f,0.f};
            #pragma unroll
            for (int kt = 0; kt < 4; ++kt) {
                u16x8 bh = *(const u16x8*)(LGb + 32 * kt + quad * 8);
                u16x8 bl = *(const u16x8*)(LGb + 128 + 32 * kt + quad * 8);
                aCh = mfma16(acf[kt], bh, aCh);
                aCl = mfma16(acf[kt], bl, aCl);
            }
            if (l4 == 0) {
                f32x4 pf = *(const f32x4*)(pPf + 16 * w + quad * 4);
                *(f32x4*)(cS + 16 * w + quad * 4) = aCh + aCl + pf;
            }
        }
        __syncthreads();   // C: c ready

        // ---- update h1 (nt 0..1) using accF from prev E-phase ----
        float hp[16];
        #pragma unroll
        for (int v = 0; v < 16; ++v) hp[v] = 0.f;
        #pragma unroll
        for (int mt = 0; mt < 4; ++mt) {
            int d0 = 64 * ih + 16 * mt + quad * 4;
            f32x4 lg = *(const f32x4*)(LGf + d0);
            f32x4 cc = *(const f32x4*)(cS + d0);
            #pragma unroll
            for (int n2 = 0; n2 < 2; ++n2) {
                int s = 64 * jh + 16 * n2 + l4;
                f32x4 hv;
                #pragma unroll
                for (int r = 0; r < 4; ++r) {
                    float e = __builtin_amdgcn_exp2f(accF[mt][n2][r] + cc[r]);
                    float f = __builtin_amdgcn_rcpf(1.f + e);
                    float hn = kvt[n2] * lg[r] + f * hreg[mt][n2][r];
                    hreg[mt][n2][r] = hn;
                    hp[mt * 4 + r] += kvn[n2] * hn;
                    hv[r] = hn;
                }
                *(u16x4*)(hS + s * RL + d0) = cvt4(hv);
            }
        }
        // ---- Zf h2 (rows not yet rewritten this step) ----
        #pragma unroll
        for (int mt = 0; mt < 4; ++mt)
            #pragma unroll
            for (int n2 = 0; n2 < 2; ++n2)
                accF[mt][n2] = (f32x4){0.f, 0.f, 0.f, 0.f};
        #pragma unroll
        for (int n2 = 0; n2 < 2; ++n2) {
            const u16* bp = hS + (64 * jh + 16 * (2 + n2) + l4) * RL + quad * 8;
            #pragma unroll
            for (int kt = 0; kt < 4; ++kt) {
                u16x8 bfr = *(const u16x8*)(bp + kt * 32);
                #pragma unroll
                for (int mt = 0; mt < 4; ++mt)
                    accF[mt][n2] = mfma16(afr[mt][kt], bfr, accF[mt][n2]);
            }
        }
        __syncthreads();   // D: all h2 reads done before h2 writes

        // ---- update h2 (nt 2..3) ----
        #pragma unroll
        for (int mt = 0; mt < 4; ++mt) {
            int d0 = 64 * ih + 16 * mt + quad * 4;
            f32x4 lg = *(const f32x4*)(LGf + d0);
            f32x4 cc = *(const f32x4*)(cS + d0);
            #pragma unroll
            for (int n2 = 0; n2 < 2; ++n2) {
                int nt = 2 + n2;
                int s = 64 * jh + 16 * nt + l4;
                f32x4 hv;
                #pragma unroll
                for (int r = 0; r < 4; ++r) {
                    float e = __builtin_amdgcn_exp2f(accF[mt][n2][r] + cc[r]);
                    float f = __builtin_amdgcn_rcpf(1.f + e);
                    float hn = kvt[nt] * lg[r] + f * hreg[mt][nt][r];
                    hreg[mt][nt][r] = hn;
                    hp[mt * 4 + r] += kvn[nt] * hn;
                    hv[r] = hn;
                }
                *(u16x4*)(hS + s * RL + d0) = cvt4(hv);
            }
        }
        // ---- h~ partial scatter ----
        #pragma unroll
        for (int mt = 0; mt < 4; ++mt)
            #pragma unroll
            for (int r = 0; r < 4; ++r)
                part[(64 * ih + 16 * mt + quad * 4 + r) * PP + jh * 16 + l4] = hp[mt * 4 + r];
        #pragma unroll
        for (int nt = 0; nt < 4; ++nt) kvt[nt] = kvn[nt];
        __syncthreads();   // E: partials ready, hS final for step t

        // ---- reduce h~ (128x4 threads) ----
        {
            int d = tid >> 2, kq = tid & 3;
            const float* pp = part + d * PP + kq * 16;
            float v = 0.f;
            #pragma unroll
            for (int i4 = 0; i4 < 4; ++i4) {
                f32x4 x = *(const f32x4*)(pp + 4 * i4);
                v += x[0] + x[1] + x[2] + x[3];
            }
            v += __shfl_xor(v, 1, 64);
            v += __shfl_xor(v, 2, 64);
            if (kq == 0) {
                float hf = (float)(__bf16)v;
                htbf[d] = bfu(v);
                htbf[128 + d] = bfu(v - hf);
                pHt[d] = v;
            }
        }
        // ---- Zf h1 for t+1 (overlaps reduce; reads h1 rows, final since pre-D) ----
        if (t < T_SZ - 1) {
            #pragma unroll
            for (int mt = 0; mt < 4; ++mt)
                #pragma unroll
                for (int n2 = 0; n2 < 2; ++n2)
                    accF[mt][n2] = (f32x4){0.f, 0.f, 0.f, 0.f};
            #pragma unroll
            for (int n2 = 0; n2 < 2; ++n2) {
                const u16* bp = hS + (64 * jh + 16 * n2 + l4) * RL + quad * 8;
                #pragma unroll
                for (int kt = 0; kt < 4; ++kt) {
                    u16x8 bfr = *(const u16x8*)(bp + kt * 32);
                    #pragma unroll
                    for (int mt = 0; mt < 4; ++mt)
                        accF[mt][n2] = mfma16(afr[mt][kt], bfr, accF[mt][n2]);
                }
            }
        }
        pPl += DK; pPg += DK; pPf += DK; pHt += DK;   // <-- R5 bug fix: advance ALL per-t pointers
        __syncthreads();   // TOP: h~ ready, part free
    }
}

// ---------------------------------------------------------------------------
// Kernel D: pred[b,t] = sigm(Wp @ [ex[b,t+1] | h_tilde[b,t]] + bp)
// ---------------------------------------------------------------------------
__global__ __launch_bounds__(128) void k_pred(
    const int* __restrict__ eid, const float* __restrict__ ex_t,
    const float* __restrict__ Wp, const float* __restrict__ bpv,
    const float* __restrict__ ht_ws, float* __restrict__ out)
{
    int t = blockIdx.x, b = blockIdx.y, d = threadIdx.x;
    __shared__ float exS[128], htS[128];
    int e = eid[b * S_SZ + t + 1];
    exS[d] = ex_t[e * DK + d];
    htS[d] = ht_ws[(size_t)(b * T_SZ + t) * DK + d];
    __syncthreads();
    const float* wr = Wp + d * 256;
    float z = bpv[d];
    #pragma unroll 8
    for (int k4 = 0; k4 < 32; ++k4) {
        f32x4 w = *(const f32x4*)(wr + 4 * k4);
        z += w[0] * exS[4 * k4] + w[1] * exS[4 * k4 + 1]
           + w[2] * exS[4 * k4 + 2] + w[3] * exS[4 * k4 + 3];
    }
    #pragma unroll 8
    for (int k4 = 32; k4 < 64; ++k4) {
        f32x4 w = *(const f32x4*)(wr + 4 * k4);
        z += w[0] * htS[4 * k4 - 128] + w[1] * htS[4 * k4 - 127]
           + w[2] * htS[4 * k4 - 126] + w[3] * htS[4 * k4 - 125];
    }
    out[(size_t)(b * T_SZ + t) * DK + d] = sigm(z);
}

extern "C" void kernel_launch(void* const* d_in, const int* in_sizes, int n_in,
                              void* d_out, int out_size, void* d_ws, size_t ws_size,
                              hipStream_t stream) {
    const int* eid     = (const int*)d_in[0];
    const int* atime   = (const int*)d_in[1];
    const int* itime   = (const int*)d_in[2];
    const int* ansv    = (const int*)d_in[3];
    const float* qmat  = (const float*)d_in[4];
    const float* ex_t  = (const float*)d_in[5];
    const float* at_t  = (const float*)d_in[6];
    const float* it_t  = (const float*)d_in[7];
    const float* W1    = (const float*)d_in[8];
    const float* b1    = (const float*)d_in[9];
    const float* Wl    = (const float*)d_in[10];
    const float* blv   = (const float*)d_in[11];
    const float* Wg    = (const float*)d_in[12];
    const float* bgv   = (const float*)d_in[13];
    const float* Wf    = (const float*)d_in[14];
    const float* bfv   = (const float*)d_in[15];
    const float* Wp    = (const float*)d_in[16];
    const float* bpv   = (const float*)d_in[17];
    const float* h0    = (const float*)d_in[18];
    float* out = (float*)d_out;

    const size_t SZ = (size_t)B_SZ * T_SZ * DK;
    float* wsf   = (float*)d_ws;
    float* PRE_l = wsf;
    float* PRE_g = wsf + SZ;
    float* PRE_f = wsf + 2 * SZ;
    float* ht_ws = wsf + 3 * SZ;

    hipFuncSetAttribute((const void*)k_main,
                        hipFuncAttributeMaxDynamicSharedMemorySize, 106496);

    dim3 g(T_SZ, B_SZ);
    k_pre <<<g, 128, 0, stream>>>(eid, atime, ansv, itime, ex_t, at_t, it_t,
                                  W1, b1, Wl, blv, Wg, bgv, Wf, bfv,
                                  PRE_l, PRE_g, PRE_f);
    k_main<<<dim3(B_SZ), 512, 106496, stream>>>(eid, qmat, Wl, Wg, Wf, h0,
                                                PRE_l, PRE_g, PRE_f, ht_ws);
    k_pred<<<g, 128, 0, stream>>>(eid, ex_t, Wp, bpv, ht_ws, out);
}